// Round 8
// baseline (282.217 us; speedup 1.0000x reference)
//
#include <hip/hip_runtime.h>
#include <hip/hip_bf16.h>
#include <stdint.h>

// y[m,o] = (sum_k x[m,k]*w_int8[o,k]) * scales[o] + bias[o]
// M=2048, N=11008, K=4096.
// Round 8: i8 MFMA, tile 256x128 (8 waves x 64x64), BK=64. A fragments load
// DIRECTLY global->VGPR (L1/L2-resident panel, frag = contiguous 16B/lane);
// only B staged in LDS (8KB/tile, 16KB dbuf). LDS traffic per block-tile
// 88KB -> 40KB, below the MFMA floor -> MFMA-bound again.
// Per tile: {4 ds_read B + 4 global A; lgkm(0); bar; stage B(t+2) in-place;
// vmcnt(1); 16 MFMA; bar}. Swizzle (verified 0-conflict) unchanged.

typedef __attribute__((ext_vector_type(8))) short short8;
typedef __attribute__((ext_vector_type(4))) float f32x4;
typedef __attribute__((ext_vector_type(4))) float float4v;
typedef __attribute__((ext_vector_type(4))) int int4v;

#define MM 2048
#define NN 11008
#define KK 4096
#define NT (KK / 64)           // 64 K-tiles of BK=64 (i8) = 64 B rows
#define ROWB ((size_t)KK)      // 4096 bytes per row (K in i8)

static __device__ __forceinline__ ushort f2bf_rne(float f) {
    uint32_t u = __builtin_bit_cast(uint32_t, f);
    u = (u + 0x7FFFu + ((u >> 16) & 1u)) >> 16;
    return (ushort)u;
}
static __device__ __forceinline__ ushort i2bf_exact(int v) {
    return (ushort)(__builtin_bit_cast(uint32_t, (float)v) >> 16);
}
static __device__ __forceinline__ void gload16(const void* g, void* lds) {
    __builtin_amdgcn_global_load_lds(
        (const __attribute__((address_space(1))) uint32_t*)g,
        (__attribute__((address_space(3))) uint32_t*)lds, 16, 0, 0);
}

// ---------------- pass 1: per-row absmax of x -> s_r, 1/s_r ----------------
__global__ __launch_bounds__(256)
void rowmax_x(const float* __restrict__ X, float* __restrict__ Sx, float* __restrict__ SxInv) {
    const int r = blockIdx.x;
    const float4v* xr = (const float4v*)(X + (size_t)r * KK);
    float m = 0.f;
    for (int i = threadIdx.x; i < KK / 4; i += 256) {
        float4v v = xr[i];
        m = fmaxf(m, fmaxf(fmaxf(fabsf(v[0]), fabsf(v[1])),
                           fmaxf(fabsf(v[2]), fabsf(v[3]))));
    }
#pragma unroll
    for (int off = 32; off; off >>= 1) m = fmaxf(m, __shfl_down(m, off));
    __shared__ float wmax[4];
    if ((threadIdx.x & 63) == 0) wmax[threadIdx.x >> 6] = m;
    __syncthreads();
    if (threadIdx.x == 0) {
        float a = fmaxf(fmaxf(wmax[0], wmax[1]), fmaxf(wmax[2], wmax[3]));
        Sx[r]    = a / 127.f;
        SxInv[r] = (a > 0.f) ? 127.f / a : 0.f;
    }
}

// ---------------- pass 2: quantize x -> i8, pack w int32 -> i8 ----------------
__global__ __launch_bounds__(256)
void quant_pack(const float* __restrict__ X, const int* __restrict__ W,
                const float* __restrict__ SxInv,
                char* __restrict__ Xq, char* __restrict__ Wq) {
    const int NX4 = MM * KK / 4;
    const int NW4 = NN * KK / 4;
    const int stride = gridDim.x * blockDim.x;
    for (int i = blockIdx.x * blockDim.x + threadIdx.x; i < NX4 + NW4; i += stride) {
        if (i < NX4) {
            float4v v = ((const float4v*)X)[i];
            const float inv = SxInv[i >> 10];
            uint32_t p = 0;
#pragma unroll
            for (int j = 0; j < 4; ++j) {
                int q = (int)rintf(v[j] * inv);
                p |= ((uint32_t)(q & 255)) << (8 * j);
            }
            ((uint32_t*)Xq)[i] = p;
        } else {
            int j = i - NX4;
            int4v w = ((const int4v*)W)[j];
            uint32_t p = ((uint32_t)(w[0] & 255)) | ((uint32_t)(w[1] & 255) << 8) |
                         ((uint32_t)(w[2] & 255) << 16) | ((uint32_t)(w[3] & 255) << 24);
            ((uint32_t*)Wq)[j] = p;
        }
    }
}

// B staging: tile = 128 rows x 64 B = 8 KB = one gload16 across 512 threads
static __device__ __forceinline__ void stageB(const char* g, char* lds, int wid, size_t kb) {
    gload16(g + kb, lds + wid * 1024);
}

// ---------------- main GEMM: 256x128 tile, BK=64 i8, B-only LDS ----------------
__global__ __launch_bounds__(512, 4)
void gemm_i8(const char* __restrict__ A, const char* __restrict__ B,
             const float* __restrict__ Sx, const float* __restrict__ S,
             const float* __restrict__ Bv, float* __restrict__ Y) {
    __shared__ char smem[16384];          // B0 8K | B1 8K
    char* bB0 = smem;
    char* bB1 = smem + 8192;

    const int tid  = threadIdx.x;
    const int lane = tid & 63;
    const int wid  = tid >> 6;
    const int wm   = wid >> 1;            // 4 M-waves (64 rows each)
    const int wn   = wid & 1;             // 2 N-waves (64 cols each)
    const int l15  = lane & 15;
    const int q    = lane >> 4;           // k-chunk 0..3 (16 i8 each)

    // XCD-aware bijective swizzle: 688 = 8 * 86
    const int swz  = (blockIdx.x & 7) * 86 + (blockIdx.x >> 3);
    const int brow = (swz / 86) * 256;    // 8 M-tiles
    const int bcol = (swz % 86) * 128;    // 86 N-tiles

    // B staging source: row tid>>2 (0..127), 16-B slot (tid&3), inverse-swizzled
    const int srow4 = tid >> 2;
    const int sslot = (tid & 3) ^ ((srow4 >> 1) & 3);
    const char* gB = B + (size_t)(bcol + srow4) * ROWB + sslot * 16;

    // A direct-load base: lane reads A[brow + wm*64 + m*16 + l15][t*64 + q*16 .. +16]
    const char* gA = A + (size_t)(brow + wm * 64 + l15) * ROWB + q * 16;

    // B ds_read offsets: 64-B rows, swizzled k-slot (verified 0-conflict in r7)
    const int rdB = (wn * 64 + l15) * 64;
    const int kq  = (q ^ ((l15 >> 1) & 3)) * 16;

#define LDB(buf, n) (*(const int4v*)((buf) + rdB + (n) * 1024 + kq))
#define LDAG(t, m)  (*(const int4v*)(gA + (size_t)(t) * 64 + (size_t)(m) * (16 * ROWB)))

    int4v acc[4][4] = {};

    // prologue: B tile0 -> bB0, tile1 -> bB1; wait tile0 (1 stays in flight)
    stageB(gB, bB0, wid, 0);
    stageB(gB, bB1, wid, 64);
    asm volatile("s_waitcnt vmcnt(1)" ::: "memory");
    __builtin_amdgcn_s_barrier();

    char* curB = bB0;
    char* nxtB = bB1;

    for (int t = 0; t < NT; ++t) {
        const size_t kb2 = (size_t)((t + 2 < NT) ? t + 2 : NT - 1) * 64;

        int4v af[4], bf[4];
#pragma unroll
        for (int n = 0; n < 4; ++n) bf[n] = LDB(curB, n);
#pragma unroll
        for (int m = 0; m < 4; ++m) af[m] = LDAG(t, m);   // global, L1/L2-resident

        // all waves' B reads retired -> safe to overwrite curB
        asm volatile("s_waitcnt lgkmcnt(0)" ::: "memory");
        __builtin_amdgcn_s_barrier();

        stageB(gB, curB, wid, kb2);    // B(t+2) in-place, distance-2 prefetch

        // retire stage(t+1) + A(t); only stage(t+2) stays in flight
        asm volatile("s_waitcnt vmcnt(1)" ::: "memory");

        __builtin_amdgcn_s_setprio(1);
#pragma unroll
        for (int m = 0; m < 4; ++m)
#pragma unroll
            for (int n = 0; n < 4; ++n)
                acc[m][n] = __builtin_amdgcn_mfma_i32_16x16x64_i8(af[m], bf[n], acc[m][n], 0, 0, 0);
        __builtin_amdgcn_s_setprio(0);

        // all waves passed vmcnt(1) -> every wave's stage(t+1) landed
        __builtin_amdgcn_s_barrier();

        char* tB = curB; curB = nxtB; nxtB = tB;
    }

    // epilogue: y = acc * (s_r[row] * scale[col]) + bias[col]
    // C/D: col = lane&15 (+n*16), row = q*4 + r (+m*16)
#pragma unroll
    for (int n = 0; n < 4; ++n) {
        const int gc = bcol + wn * 64 + n * 16 + l15;
        const float sj = S[gc];
        const float bj = Bv[gc];
#pragma unroll
        for (int m = 0; m < 4; ++m) {
            const int grow = brow + wm * 64 + m * 16 + q * 4;
            float* yp = Y + (size_t)grow * NN + gc;
#pragma unroll
            for (int r = 0; r < 4; ++r)
                yp[(size_t)r * NN] = (float)acc[m][n][r] * (Sx[grow + r] * sj) + bj;
        }
    }
#undef LDB
#undef LDAG
}

// ---------------- fallback (fused bf16 kernel, no ws needed) ----------------
#define BMF 128
#define BKF 32
#define LDW (BKF + 8)
__global__ __launch_bounds__(256, 2)
void int8lin_fused(const float* __restrict__ X, const int* __restrict__ W,
                   const float* __restrict__ S, const float* __restrict__ Bv,
                   float* __restrict__ Y) {
    __shared__ ushort As[BMF][LDW];
    __shared__ ushort Bs[BMF][LDW];
    const int tid = threadIdx.x, lane = tid & 63, wid = tid >> 6;
    const int wm = wid >> 1, wn = wid & 1, l15 = lane & 15, kh = (lane >> 4) * 8;
    const int bm = blockIdx.x & 15, bn = blockIdx.x >> 4;
    const int brow = bm * BMF, bcol = bn * BMF;
    const int srow = tid >> 1, scol = (tid & 1) * 16;
    const float* xg = X + (size_t)(brow + srow) * KK + scol;
    const int*   wg = W + (size_t)(bcol + srow) * KK + scol;
    f32x4 acc[4][4] = {};
    for (int kt = 0; kt < KK / BKF; ++kt) {
        float4v x0 = *(const float4v*)(xg + 0), x1 = *(const float4v*)(xg + 4);
        float4v x2 = *(const float4v*)(xg + 8), x3 = *(const float4v*)(xg + 12);
        int4v w0 = *(const int4v*)(wg + 0), w1 = *(const int4v*)(wg + 4);
        int4v w2 = *(const int4v*)(wg + 8), w3 = *(const int4v*)(wg + 12);
        xg += BKF; wg += BKF;
        short8 xa = { (short)f2bf_rne(x0[0]), (short)f2bf_rne(x0[1]), (short)f2bf_rne(x0[2]), (short)f2bf_rne(x0[3]),
                      (short)f2bf_rne(x1[0]), (short)f2bf_rne(x1[1]), (short)f2bf_rne(x1[2]), (short)f2bf_rne(x1[3]) };
        short8 xb = { (short)f2bf_rne(x2[0]), (short)f2bf_rne(x2[1]), (short)f2bf_rne(x2[2]), (short)f2bf_rne(x2[3]),
                      (short)f2bf_rne(x3[0]), (short)f2bf_rne(x3[1]), (short)f2bf_rne(x3[2]), (short)f2bf_rne(x3[3]) };
        short8 wa = { (short)i2bf_exact(w0[0]), (short)i2bf_exact(w0[1]), (short)i2bf_exact(w0[2]), (short)i2bf_exact(w0[3]),
                      (short)i2bf_exact(w1[0]), (short)i2bf_exact(w1[1]), (short)i2bf_exact(w1[2]), (short)i2bf_exact(w1[3]) };
        short8 wb = { (short)i2bf_exact(w2[0]), (short)i2bf_exact(w2[1]), (short)i2bf_exact(w2[2]), (short)i2bf_exact(w2[3]),
                      (short)i2bf_exact(w3[0]), (short)i2bf_exact(w3[1]), (short)i2bf_exact(w3[2]), (short)i2bf_exact(w3[3]) };
        __syncthreads();
        *(short8*)&As[srow][scol] = xa; *(short8*)&As[srow][scol + 8] = xb;
        *(short8*)&Bs[srow][scol] = wa; *(short8*)&Bs[srow][scol + 8] = wb;
        __syncthreads();
        short8 af[4], bf4[4];
#pragma unroll
        for (int i = 0; i < 4; ++i) af[i] = *(const short8*)&As[wm * 64 + i * 16 + l15][kh];
#pragma unroll
        for (int j = 0; j < 4; ++j) bf4[j] = *(const short8*)&Bs[wn * 64 + j * 16 + l15][kh];
#pragma unroll
        for (int i = 0; i < 4; ++i)
#pragma unroll
            for (int j = 0; j < 4; ++j)
                acc[i][j] = __builtin_amdgcn_mfma_f32_16x16x32_bf16(af[i], bf4[j], acc[i][j], 0, 0, 0);
    }
#pragma unroll
    for (int j = 0; j < 4; ++j) {
        const int gc = bcol + wn * 64 + j * 16 + l15;
        const float sj = S[gc], bj = Bv[gc];
#pragma unroll
        for (int i = 0; i < 4; ++i) {
            const int grow = brow + wm * 64 + i * 16 + (lane >> 4) * 4;
            float* yp = Y + (size_t)grow * NN + gc;
#pragma unroll
            for (int r = 0; r < 4; ++r)
                yp[(size_t)r * NN] = acc[i][j][r] * sj + bj;
        }
    }
}

extern "C" void kernel_launch(void* const* d_in, const int* in_sizes, int n_in,
                              void* d_out, int out_size, void* d_ws, size_t ws_size,
                              hipStream_t stream) {
    const float* x = (const float*)d_in[0];
    const int*   w = (const int*)d_in[1];
    const float* s = (const float*)d_in[2];
    const float* b = (const float*)d_in[3];
    float* y = (float*)d_out;

    const size_t wq_b = (size_t)NN * KK;            // 45.1 MB
    const size_t xq_b = (size_t)MM * KK;            // 8.4 MB
    const size_t need = wq_b + xq_b + 2 * MM * sizeof(float) + 256;
    if (ws_size >= need) {
        char*  Wq    = (char*)d_ws;
        char*  Xq    = Wq + wq_b;
        float* Sx    = (float*)(Xq + xq_b);
        float* SxInv = Sx + MM;
        hipLaunchKernelGGL(rowmax_x,   dim3(MM),   dim3(256), 0, stream, x, Sx, SxInv);
        hipLaunchKernelGGL(quant_pack, dim3(4096), dim3(256), 0, stream, x, w, SxInv, Xq, Wq);
        hipLaunchKernelGGL(gemm_i8, dim3((MM / 256) * (NN / 128)), dim3(512), 0, stream,
                           Xq, Wq, Sx, s, b, y);
    } else {
        hipLaunchKernelGGL(int8lin_fused, dim3((MM / BMF) * (NN / BMF)), dim3(256), 0, stream,
                           x, w, s, b, y);
    }
}

// Round 9
// 186.320 us; speedup vs baseline: 1.5147x; 1.5147x over previous
//
#include <hip/hip_runtime.h>
#include <hip/hip_bf16.h>
#include <stdint.h>

// y[m,o] = (sum_k x[m,k]*w_int8[o,k]) * scales[o] + bias[o]
// M=2048, N=11008, K=4096.
// Round 9: i8 MFMA, 256x128 tile (8 waves x 64x64), BK=64. B staged in LDS
// (r7 path, verified). A held in REGISTERS: Xq repacked k-chunk-major
// (addr = (k/16)*32768 + m*16 + k%16) so a fragment load = 4x256B coalesced
// segments (fixes r8's L1 set-camping), with distance-1 register double-buffer
// (fixes r8's no-prefetch). vmcnt(5) = stage(t+1) + afn*4 + stage(t+2) ledger.

typedef __attribute__((ext_vector_type(8))) short short8;
typedef __attribute__((ext_vector_type(4))) float f32x4;
typedef __attribute__((ext_vector_type(4))) float float4v;
typedef __attribute__((ext_vector_type(4))) int int4v;

#define MM 2048
#define NN 11008
#define KK 4096
#define NT (KK / 64)           // 64 K-tiles of BK=64
#define ROWB ((size_t)KK)      // 4096 B per W row (i8)

static __device__ __forceinline__ ushort f2bf_rne(float f) {
    uint32_t u = __builtin_bit_cast(uint32_t, f);
    u = (u + 0x7FFFu + ((u >> 16) & 1u)) >> 16;
    return (ushort)u;
}
static __device__ __forceinline__ ushort i2bf_exact(int v) {
    return (ushort)(__builtin_bit_cast(uint32_t, (float)v) >> 16);
}
static __device__ __forceinline__ void gload16(const void* g, void* lds) {
    __builtin_amdgcn_global_load_lds(
        (const __attribute__((address_space(1))) uint32_t*)g,
        (__attribute__((address_space(3))) uint32_t*)lds, 16, 0, 0);
}

// ---------------- pass 1: per-row absmax of x -> s_r, 1/s_r ----------------
__global__ __launch_bounds__(256)
void rowmax_x(const float* __restrict__ X, float* __restrict__ Sx, float* __restrict__ SxInv) {
    const int r = blockIdx.x;
    const float4v* xr = (const float4v*)(X + (size_t)r * KK);
    float m = 0.f;
    for (int i = threadIdx.x; i < KK / 4; i += 256) {
        float4v v = xr[i];
        m = fmaxf(m, fmaxf(fmaxf(fabsf(v[0]), fabsf(v[1])),
                           fmaxf(fabsf(v[2]), fabsf(v[3]))));
    }
#pragma unroll
    for (int off = 32; off; off >>= 1) m = fmaxf(m, __shfl_down(m, off));
    __shared__ float wmax[4];
    if ((threadIdx.x & 63) == 0) wmax[threadIdx.x >> 6] = m;
    __syncthreads();
    if (threadIdx.x == 0) {
        float a = fmaxf(fmaxf(wmax[0], wmax[1]), fmaxf(wmax[2], wmax[3]));
        Sx[r]    = a / 127.f;
        SxInv[r] = (a > 0.f) ? 127.f / a : 0.f;
    }
}

// ------- pass 2: quantize x -> i8 (k-chunk-major layout), pack w -> i8 -------
// Xq layout: byte addr = (k/16)*(MM*16) + m*16 + (k%16); MM*16 = 32768.
__global__ __launch_bounds__(256)
void quant_pack(const float* __restrict__ X, const int* __restrict__ W,
                const float* __restrict__ SxInv,
                char* __restrict__ Xq, char* __restrict__ Wq) {
    const int NX4 = MM * KK / 4;
    const int NW4 = NN * KK / 4;
    const int stride = gridDim.x * blockDim.x;
    for (int i = blockIdx.x * blockDim.x + threadIdx.x; i < NX4 + NW4; i += stride) {
        if (i < NX4) {
            float4v v = ((const float4v*)X)[i];
            const int m   = i >> 10;          // row (KK/4 = 1024 chunks per row)
            const int kq4 = i & 1023;         // k/4
            const float inv = SxInv[m];
            uint32_t p = 0;
#pragma unroll
            for (int j = 0; j < 4; ++j) {
                int q = (int)rintf(v[j] * inv);
                p |= ((uint32_t)(q & 255)) << (8 * j);
            }
            *(uint32_t*)(Xq + (((size_t)(kq4 >> 2)) << 15) + m * 16 + ((kq4 & 3) << 2)) = p;
        } else {
            int j = i - NX4;
            int4v w = ((const int4v*)W)[j];
            uint32_t p = ((uint32_t)(w[0] & 255)) | ((uint32_t)(w[1] & 255) << 8) |
                         ((uint32_t)(w[2] & 255) << 16) | ((uint32_t)(w[3] & 255) << 24);
            ((uint32_t*)Wq)[j] = p;
        }
    }
}

// B staging: tile = 128 rows x 64 B = 8 KB = one gload16 across 512 threads
static __device__ __forceinline__ void stageB(const char* g, char* lds, int wid, size_t kb) {
    gload16(g + kb, lds + wid * 1024);
}

// ---------------- main GEMM: 256x128 tile, BK=64 i8, A-in-regs ----------------
__global__ __launch_bounds__(512, 4)
void gemm_i8(const char* __restrict__ A, const char* __restrict__ B,
             const float* __restrict__ Sx, const float* __restrict__ S,
             const float* __restrict__ Bv, float* __restrict__ Y) {
    __shared__ char smem[16384];          // B0 8K | B1 8K
    char* bB0 = smem;
    char* bB1 = smem + 8192;

    const int tid  = threadIdx.x;
    const int lane = tid & 63;
    const int wid  = tid >> 6;
    const int wm   = wid >> 1;            // 4 M-waves (64 rows each)
    const int wn   = wid & 1;             // 2 N-waves (64 cols each)
    const int l15  = lane & 15;
    const int q    = lane >> 4;           // k-chunk 0..3

    // XCD-aware bijective swizzle: 688 = 8 * 86
    const int swz  = (blockIdx.x & 7) * 86 + (blockIdx.x >> 3);
    const int brow = (swz / 86) * 256;
    const int bcol = (swz % 86) * 128;

    // B staging source (r7, verified): row tid>>2, slot (tid&3) inverse-swizzled
    const int srow4 = tid >> 2;
    const int sslot = (tid & 3) ^ ((srow4 >> 1) & 3);
    const char* gB = B + (size_t)(bcol + srow4) * ROWB + sslot * 16;

    // A base in k-chunk-major layout: lane reads 16B at chunk (t*4+q), row brow+wm*64+m*16+l15
    const char* gA = A + (((size_t)q) << 15) + (size_t)(brow + wm * 64 + l15) * 16;
#define LDAG(t, m) (*(const int4v*)(gA + (size_t)(t) * 131072 + (m) * 256))

    // B ds_read offsets (r7, verified 0-conflict)
    const int rdB = (wn * 64 + l15) * 64;
    const int kq  = (q ^ ((l15 >> 1) & 3)) * 16;
#define LDB(buf, n) (*(const int4v*)((buf) + rdB + (n) * 1024 + kq))

    int4v acc[4][4] = {};
    int4v af[4], afn[4], bf[4];

    // ---- prologue: stage B(0), B(1); wait B(0); then load A(0) after the fence
    stageB(gB, bB0, wid, 0);
    stageB(gB, bB1, wid, 64);
    asm volatile("s_waitcnt vmcnt(1)" ::: "memory");
    __builtin_amdgcn_s_barrier();
#pragma unroll
    for (int m = 0; m < 4; ++m) af[m] = LDAG(0, m);

    char* curB = bB0;
    char* nxtB = bB1;

    // Per-iter ledger at vmcnt(5): in-flight = stage(t+1), afn(t+1)x4, stage(t+2)
    // (iter 0 additionally has af(0)x4, drained by the same wait). Ordering of
    // loads vs stage builtins pinned by the "memory" fences between regions.
#define GEMM_ITER(AFc, AFn, T)                                                   \
    {                                                                            \
        const int tt = (T);                                                      \
        const size_t kb2 = (size_t)((tt + 2 < NT) ? tt + 2 : NT - 1) * 64;       \
        const int tn = (tt + 1 < NT) ? tt + 1 : NT - 1;                          \
        _Pragma("unroll")                                                        \
        for (int n = 0; n < 4; ++n) bf[n] = LDB(curB, n);                        \
        _Pragma("unroll")                                                        \
        for (int m = 0; m < 4; ++m) AFn[m] = LDAG(tn, m);                        \
        asm volatile("s_waitcnt lgkmcnt(0)" ::: "memory");                       \
        __builtin_amdgcn_s_barrier();                                            \
        stageB(gB, curB, wid, kb2);                                              \
        asm volatile("s_waitcnt vmcnt(5)" ::: "memory");                         \
        __builtin_amdgcn_s_setprio(1);                                           \
        _Pragma("unroll")                                                        \
        for (int m = 0; m < 4; ++m)                                              \
            _Pragma("unroll")                                                    \
            for (int n = 0; n < 4; ++n)                                          \
                acc[m][n] = __builtin_amdgcn_mfma_i32_16x16x64_i8(AFc[m], bf[n], acc[m][n], 0, 0, 0); \
        __builtin_amdgcn_s_setprio(0);                                           \
        __builtin_amdgcn_s_barrier();                                            \
        { char* tmp = curB; curB = nxtB; nxtB = tmp; }                           \
    }

    for (int t = 0; t < NT; t += 2) {
        GEMM_ITER(af, afn, t);
        GEMM_ITER(afn, af, t + 1);
    }
#undef GEMM_ITER

    // epilogue: y = acc * (s_r[row] * scale[col]) + bias[col]
    // C/D: col = lane&15 (+n*16), row = q*4 + r (+m*16)
#pragma unroll
    for (int n = 0; n < 4; ++n) {
        const int gc = bcol + wn * 64 + n * 16 + l15;
        const float sj = S[gc];
        const float bj = Bv[gc];
#pragma unroll
        for (int m = 0; m < 4; ++m) {
            const int grow = brow + wm * 64 + m * 16 + q * 4;
            float* yp = Y + (size_t)grow * NN + gc;
#pragma unroll
            for (int r = 0; r < 4; ++r)
                yp[(size_t)r * NN] = (float)acc[m][n][r] * (Sx[grow + r] * sj) + bj;
        }
    }
#undef LDB
#undef LDAG
}

// ---------------- fallback (fused bf16 kernel, no ws needed) ----------------
#define BMF 128
#define BKF 32
#define LDW (BKF + 8)
__global__ __launch_bounds__(256, 2)
void int8lin_fused(const float* __restrict__ X, const int* __restrict__ W,
                   const float* __restrict__ S, const float* __restrict__ Bv,
                   float* __restrict__ Y) {
    __shared__ ushort As[BMF][LDW];
    __shared__ ushort Bs[BMF][LDW];
    const int tid = threadIdx.x, lane = tid & 63, wid = tid >> 6;
    const int wm = wid >> 1, wn = wid & 1, l15 = lane & 15, kh = (lane >> 4) * 8;
    const int bm = blockIdx.x & 15, bn = blockIdx.x >> 4;
    const int brow = bm * BMF, bcol = bn * BMF;
    const int srow = tid >> 1, scol = (tid & 1) * 16;
    const float* xg = X + (size_t)(brow + srow) * KK + scol;
    const int*   wg = W + (size_t)(bcol + srow) * KK + scol;
    f32x4 acc[4][4] = {};
    for (int kt = 0; kt < KK / BKF; ++kt) {
        float4v x0 = *(const float4v*)(xg + 0), x1 = *(const float4v*)(xg + 4);
        float4v x2 = *(const float4v*)(xg + 8), x3 = *(const float4v*)(xg + 12);
        int4v w0 = *(const int4v*)(wg + 0), w1 = *(const int4v*)(wg + 4);
        int4v w2 = *(const int4v*)(wg + 8), w3 = *(const int4v*)(wg + 12);
        xg += BKF; wg += BKF;
        short8 xa = { (short)f2bf_rne(x0[0]), (short)f2bf_rne(x0[1]), (short)f2bf_rne(x0[2]), (short)f2bf_rne(x0[3]),
                      (short)f2bf_rne(x1[0]), (short)f2bf_rne(x1[1]), (short)f2bf_rne(x1[2]), (short)f2bf_rne(x1[3]) };
        short8 xb = { (short)f2bf_rne(x2[0]), (short)f2bf_rne(x2[1]), (short)f2bf_rne(x2[2]), (short)f2bf_rne(x2[3]),
                      (short)f2bf_rne(x3[0]), (short)f2bf_rne(x3[1]), (short)f2bf_rne(x3[2]), (short)f2bf_rne(x3[3]) };
        short8 wa = { (short)i2bf_exact(w0[0]), (short)i2bf_exact(w0[1]), (short)i2bf_exact(w0[2]), (short)i2bf_exact(w0[3]),
                      (short)i2bf_exact(w1[0]), (short)i2bf_exact(w1[1]), (short)i2bf_exact(w1[2]), (short)i2bf_exact(w1[3]) };
        short8 wb = { (short)i2bf_exact(w2[0]), (short)i2bf_exact(w2[1]), (short)i2bf_exact(w2[2]), (short)i2bf_exact(w2[3]),
                      (short)i2bf_exact(w3[0]), (short)i2bf_exact(w3[1]), (short)i2bf_exact(w3[2]), (short)i2bf_exact(w3[3]) };
        __syncthreads();
        *(short8*)&As[srow][scol] = xa; *(short8*)&As[srow][scol + 8] = xb;
        *(short8*)&Bs[srow][scol] = wa; *(short8*)&Bs[srow][scol + 8] = wb;
        __syncthreads();
        short8 af2[4], bf4[4];
#pragma unroll
        for (int i = 0; i < 4; ++i) af2[i] = *(const short8*)&As[wm * 64 + i * 16 + l15][kh];
#pragma unroll
        for (int j = 0; j < 4; ++j) bf4[j] = *(const short8*)&Bs[wn * 64 + j * 16 + l15][kh];
#pragma unroll
        for (int i = 0; i < 4; ++i)
#pragma unroll
            for (int j = 0; j < 4; ++j)
                acc[i][j] = __builtin_amdgcn_mfma_f32_16x16x32_bf16(af2[i], bf4[j], acc[i][j], 0, 0, 0);
    }
#pragma unroll
    for (int j = 0; j < 4; ++j) {
        const int gc = bcol + wn * 64 + j * 16 + l15;
        const float sj = S[gc], bj = Bv[gc];
#pragma unroll
        for (int i = 0; i < 4; ++i) {
            const int grow = brow + wm * 64 + i * 16 + (lane >> 4) * 4;
            float* yp = Y + (size_t)grow * NN + gc;
#pragma unroll
            for (int r = 0; r < 4; ++r)
                yp[(size_t)r * NN] = acc[i][j][r] * sj + bj;
        }
    }
}

extern "C" void kernel_launch(void* const* d_in, const int* in_sizes, int n_in,
                              void* d_out, int out_size, void* d_ws, size_t ws_size,
                              hipStream_t stream) {
    const float* x = (const float*)d_in[0];
    const int*   w = (const int*)d_in[1];
    const float* s = (const float*)d_in[2];
    const float* b = (const float*)d_in[3];
    float* y = (float*)d_out;

    const size_t wq_b = (size_t)NN * KK;            // 45.1 MB
    const size_t xq_b = (size_t)MM * KK;            // 8.4 MB
    const size_t need = wq_b + xq_b + 2 * MM * sizeof(float) + 256;
    if (ws_size >= need) {
        char*  Wq    = (char*)d_ws;
        char*  Xq    = Wq + wq_b;
        float* Sx    = (float*)(Xq + xq_b);
        float* SxInv = Sx + MM;
        hipLaunchKernelGGL(rowmax_x,   dim3(MM),   dim3(256), 0, stream, x, Sx, SxInv);
        hipLaunchKernelGGL(quant_pack, dim3(4096), dim3(256), 0, stream, x, w, SxInv, Xq, Wq);
        hipLaunchKernelGGL(gemm_i8, dim3((MM / 256) * (NN / 128)), dim3(512), 0, stream,
                           Xq, Wq, Sx, s, b, y);
    } else {
        hipLaunchKernelGGL(int8lin_fused, dim3((MM / BMF) * (NN / BMF)), dim3(256), 0, stream,
                           x, w, s, b, y);
    }
}

// Round 10
// 162.101 us; speedup vs baseline: 1.7410x; 1.1494x over previous
//
#include <hip/hip_runtime.h>
#include <hip/hip_bf16.h>
#include <stdint.h>

// y[m,o] = (sum_k x[m,k]*w_int8[o,k]) * scales[o] + bias[o]
// M=2048, N=11008, K=4096.
// Round 10: r7 geometry (i8 MFMA, 256x128 tile, 8 waves x 64x64, BK=64,
// 2 blocks/CU) with TRIPLE-buffered LDS: read buf[t%3], stage buf[(t+2)%3]
// (last read at tile t-1, retired before t-1's barrier) -> no WAR -> no
// lgkmcnt(0) drain, ONE barrier/tile, vmcnt(3) after MFMA (fully covered).
// Per tile: {8 ds_read || 3 gload_lds || 16 MFMA(setprio)} vmcnt(3) bar.

typedef __attribute__((ext_vector_type(8))) short short8;
typedef __attribute__((ext_vector_type(4))) float f32x4;
typedef __attribute__((ext_vector_type(4))) float float4v;
typedef __attribute__((ext_vector_type(4))) int int4v;

#define MM 2048
#define NN 11008
#define KK 4096
#define NT (KK / 64)           // 64 K-tiles of BK=64 (i8) = 64 B rows
#define ROWB ((size_t)KK)      // 4096 bytes per row (K in i8)

static __device__ __forceinline__ ushort f2bf_rne(float f) {
    uint32_t u = __builtin_bit_cast(uint32_t, f);
    u = (u + 0x7FFFu + ((u >> 16) & 1u)) >> 16;
    return (ushort)u;
}
static __device__ __forceinline__ ushort i2bf_exact(int v) {
    return (ushort)(__builtin_bit_cast(uint32_t, (float)v) >> 16);
}
static __device__ __forceinline__ void gload16(const void* g, void* lds) {
    __builtin_amdgcn_global_load_lds(
        (const __attribute__((address_space(1))) uint32_t*)g,
        (__attribute__((address_space(3))) uint32_t*)lds, 16, 0, 0);
}

#define BAR() do { asm volatile("" ::: "memory"); __builtin_amdgcn_s_barrier(); asm volatile("" ::: "memory"); } while (0)

// ---------------- pass 1: per-row absmax of x -> s_r, 1/s_r ----------------
__global__ __launch_bounds__(256)
void rowmax_x(const float* __restrict__ X, float* __restrict__ Sx, float* __restrict__ SxInv) {
    const int r = blockIdx.x;
    const float4v* xr = (const float4v*)(X + (size_t)r * KK);
    float m = 0.f;
    for (int i = threadIdx.x; i < KK / 4; i += 256) {
        float4v v = xr[i];
        m = fmaxf(m, fmaxf(fmaxf(fabsf(v[0]), fabsf(v[1])),
                           fmaxf(fabsf(v[2]), fabsf(v[3]))));
    }
#pragma unroll
    for (int off = 32; off; off >>= 1) m = fmaxf(m, __shfl_down(m, off));
    __shared__ float wmax[4];
    if ((threadIdx.x & 63) == 0) wmax[threadIdx.x >> 6] = m;
    __syncthreads();
    if (threadIdx.x == 0) {
        float a = fmaxf(fmaxf(wmax[0], wmax[1]), fmaxf(wmax[2], wmax[3]));
        Sx[r]    = a / 127.f;
        SxInv[r] = (a > 0.f) ? 127.f / a : 0.f;
    }
}

// ---------------- pass 2: quantize x -> i8, pack w int32 -> i8 (row-major) ----
__global__ __launch_bounds__(256)
void quant_pack(const float* __restrict__ X, const int* __restrict__ W,
                const float* __restrict__ SxInv,
                char* __restrict__ Xq, char* __restrict__ Wq) {
    const int NX4 = MM * KK / 4;
    const int NW4 = NN * KK / 4;
    const int stride = gridDim.x * blockDim.x;
    for (int i = blockIdx.x * blockDim.x + threadIdx.x; i < NX4 + NW4; i += stride) {
        if (i < NX4) {
            float4v v = ((const float4v*)X)[i];
            const float inv = SxInv[i >> 10];
            uint32_t p = 0;
#pragma unroll
            for (int j = 0; j < 4; ++j) {
                int q = (int)rintf(v[j] * inv);
                p |= ((uint32_t)(q & 255)) << (8 * j);
            }
            ((uint32_t*)Xq)[i] = p;
        } else {
            int j = i - NX4;
            int4v w = ((const int4v*)W)[j];
            uint32_t p = ((uint32_t)(w[0] & 255)) | ((uint32_t)(w[1] & 255) << 8) |
                         ((uint32_t)(w[2] & 255) << 16) | ((uint32_t)(w[3] & 255) << 24);
            ((uint32_t*)Wq)[j] = p;
        }
    }
}

// staging: A tile = 256 rows x 64 B = 16 KB (2 issues); B tile = 128 x 64 B = 8 KB (1)
static __device__ __forceinline__ void stageA(const char* g, char* lds, int wid, size_t kb) {
    gload16(g + kb,                       lds + wid * 1024);
    gload16(g + kb + (size_t)128 * ROWB,  lds + 8192 + wid * 1024);
}
static __device__ __forceinline__ void stageB(const char* g, char* lds, int wid, size_t kb) {
    gload16(g + kb, lds + wid * 1024);
}

// ---------------- main GEMM: 256x128 tile, BK=64 i8, triple-buffered ----------------
__global__ __launch_bounds__(512, 4)
void gemm_i8(const char* __restrict__ A, const char* __restrict__ B,
             const float* __restrict__ Sx, const float* __restrict__ S,
             const float* __restrict__ Bv, float* __restrict__ Y) {
    __shared__ char smem[73728];          // A0|A1|A2 (16K each) + B0|B1|B2 (8K each)
    char* bA0 = smem;
    char* bA1 = smem + 16384;
    char* bA2 = smem + 32768;
    char* bB0 = smem + 49152;
    char* bB1 = smem + 57344;
    char* bB2 = smem + 65536;

    const int tid  = threadIdx.x;
    const int lane = tid & 63;
    const int wid  = tid >> 6;
    const int wm   = wid >> 1;            // 4 M-waves (64 rows each)
    const int wn   = wid & 1;             // 2 N-waves (64 cols each)
    const int l15  = lane & 15;
    const int q    = lane >> 4;           // k-chunk 0..3 (16 i8 each)

    // XCD-aware bijective swizzle: 688 = 8 * 86
    const int swz  = (blockIdx.x & 7) * 86 + (blockIdx.x >> 3);
    const int brow = (swz / 86) * 256;    // 8 M-tiles
    const int bcol = (swz % 86) * 128;    // 86 N-tiles

    // staging source: thread covers row tid>>2, 16-B slot (tid&3), inverse-swizzled
    const int srow4 = tid >> 2;                       // 0..127
    const int sslot = (tid & 3) ^ ((srow4 >> 1) & 3);
    const char* gA = A + (size_t)(brow + srow4) * ROWB + sslot * 16;
    const char* gB = B + (size_t)(bcol + srow4) * ROWB + sslot * 16;

    // ds_read offsets: 64-B rows; swizzled k-slot (verified 0-conflict, r7)
    const int rdA = (wm * 64 + l15) * 64;
    const int rdB = (wn * 64 + l15) * 64;
    const int kq  = (q ^ ((l15 >> 1) & 3)) * 16;

#define LDA(buf, m) (*(const int4v*)((buf) + rdA + (m) * 1024 + kq))
#define LDB(buf, n) (*(const int4v*)((buf) + rdB + (n) * 1024 + kq))

    int4v acc[4][4] = {};

    // prologue: tile0 -> buf0, tile1 -> buf1 (3 issues each); retire tile0 only
    stageA(gA, bA0, wid, 0);
    stageB(gB, bB0, wid, 0);
    stageA(gA, bA1, wid, 64);
    stageB(gB, bB1, wid, 64);
    asm volatile("s_waitcnt vmcnt(3)" ::: "memory");
    BAR();

    char* cA = bA0; char* nA = bA1; char* pA = bA2;   // cur / next / stage-target
    char* cB = bB0; char* nB = bB1; char* pB = bB2;

    for (int t = 0; t < NT; ++t) {
        const size_t kb2 = (size_t)((t + 2 < NT) ? t + 2 : NT - 1) * 64;

        int4v af[4], bf[4];
#pragma unroll
        for (int m = 0; m < 4; ++m) af[m] = LDA(cA, m);
#pragma unroll
        for (int n = 0; n < 4; ++n) bf[n] = LDB(cB, n);

        // stage tile t+2 into the 3rd buffer: its last readers were tile t-1,
        // whose ds_reads all retired before t-1's closing barrier -> no WAR.
        stageA(gA, pA, wid, kb2);
        stageB(gB, pB, wid, kb2);

        // compiler inserts fine-grained lgkmcnt before each MFMA operand use
        __builtin_amdgcn_s_setprio(1);
#pragma unroll
        for (int m = 0; m < 4; ++m)
#pragma unroll
            for (int n = 0; n < 4; ++n)
                acc[m][n] = __builtin_amdgcn_mfma_i32_16x16x64_i8(af[m], bf[n], acc[m][n], 0, 0, 0);
        __builtin_amdgcn_s_setprio(0);

        // retire tile t+1's 3 stages (issued last iter); keep t+2's 3 in flight
        asm volatile("s_waitcnt vmcnt(3)" ::: "memory");
        BAR();

        char* tmp;
        tmp = cA; cA = nA; nA = pA; pA = tmp;
        tmp = cB; cB = nB; nB = pB; pB = tmp;
    }

    // epilogue: y = acc * (s_r[row] * scale[col]) + bias[col]
    // C/D: col = lane&15 (+n*16), row = q*4 + r (+m*16)
#pragma unroll
    for (int n = 0; n < 4; ++n) {
        const int gc = bcol + wn * 64 + n * 16 + l15;
        const float sj = S[gc];
        const float bj = Bv[gc];
#pragma unroll
        for (int m = 0; m < 4; ++m) {
            const int grow = brow + wm * 64 + m * 16 + q * 4;
            float* yp = Y + (size_t)grow * NN + gc;
#pragma unroll
            for (int r = 0; r < 4; ++r)
                yp[(size_t)r * NN] = (float)acc[m][n][r] * (Sx[grow + r] * sj) + bj;
        }
    }
#undef LDA
#undef LDB
}

// ---------------- fallback (fused bf16 kernel, no ws needed) ----------------
#define BMF 128
#define BKF 32
#define LDW (BKF + 8)
__global__ __launch_bounds__(256, 2)
void int8lin_fused(const float* __restrict__ X, const int* __restrict__ W,
                   const float* __restrict__ S, const float* __restrict__ Bv,
                   float* __restrict__ Y) {
    __shared__ ushort As[BMF][LDW];
    __shared__ ushort Bs[BMF][LDW];
    const int tid = threadIdx.x, lane = tid & 63, wid = tid >> 6;
    const int wm = wid >> 1, wn = wid & 1, l15 = lane & 15, kh = (lane >> 4) * 8;
    const int bm = blockIdx.x & 15, bn = blockIdx.x >> 4;
    const int brow = bm * BMF, bcol = bn * BMF;
    const int srow = tid >> 1, scol = (tid & 1) * 16;
    const float* xg = X + (size_t)(brow + srow) * KK + scol;
    const int*   wg = W + (size_t)(bcol + srow) * KK + scol;
    f32x4 acc[4][4] = {};
    for (int kt = 0; kt < KK / BKF; ++kt) {
        float4v x0 = *(const float4v*)(xg + 0), x1 = *(const float4v*)(xg + 4);
        float4v x2 = *(const float4v*)(xg + 8), x3 = *(const float4v*)(xg + 12);
        int4v w0 = *(const int4v*)(wg + 0), w1 = *(const int4v*)(wg + 4);
        int4v w2 = *(const int4v*)(wg + 8), w3 = *(const int4v*)(wg + 12);
        xg += BKF; wg += BKF;
        short8 xa = { (short)f2bf_rne(x0[0]), (short)f2bf_rne(x0[1]), (short)f2bf_rne(x0[2]), (short)f2bf_rne(x0[3]),
                      (short)f2bf_rne(x1[0]), (short)f2bf_rne(x1[1]), (short)f2bf_rne(x1[2]), (short)f2bf_rne(x1[3]) };
        short8 xb = { (short)f2bf_rne(x2[0]), (short)f2bf_rne(x2[1]), (short)f2bf_rne(x2[2]), (short)f2bf_rne(x2[3]),
                      (short)f2bf_rne(x3[0]), (short)f2bf_rne(x3[1]), (short)f2bf_rne(x3[2]), (short)f2bf_rne(x3[3]) };
        short8 wa = { (short)i2bf_exact(w0[0]), (short)i2bf_exact(w0[1]), (short)i2bf_exact(w0[2]), (short)i2bf_exact(w0[3]),
                      (short)i2bf_exact(w1[0]), (short)i2bf_exact(w1[1]), (short)i2bf_exact(w1[2]), (short)i2bf_exact(w1[3]) };
        short8 wb = { (short)i2bf_exact(w2[0]), (short)i2bf_exact(w2[1]), (short)i2bf_exact(w2[2]), (short)i2bf_exact(w2[3]),
                      (short)i2bf_exact(w3[0]), (short)i2bf_exact(w3[1]), (short)i2bf_exact(w3[2]), (short)i2bf_exact(w3[3]) };
        __syncthreads();
        *(short8*)&As[srow][scol] = xa; *(short8*)&As[srow][scol + 8] = xb;
        *(short8*)&Bs[srow][scol] = wa; *(short8*)&Bs[srow][scol + 8] = wb;
        __syncthreads();
        short8 af2[4], bf4[4];
#pragma unroll
        for (int i = 0; i < 4; ++i) af2[i] = *(const short8*)&As[wm * 64 + i * 16 + l15][kh];
#pragma unroll
        for (int j = 0; j < 4; ++j) bf4[j] = *(const short8*)&Bs[wn * 64 + j * 16 + l15][kh];
#pragma unroll
        for (int i = 0; i < 4; ++i)
#pragma unroll
            for (int j = 0; j < 4; ++j)
                acc[i][j] = __builtin_amdgcn_mfma_f32_16x16x32_bf16(af2[i], bf4[j], acc[i][j], 0, 0, 0);
    }
#pragma unroll
    for (int j = 0; j < 4; ++j) {
        const int gc = bcol + wn * 64 + j * 16 + l15;
        const float sj = S[gc], bj = Bv[gc];
#pragma unroll
        for (int i = 0; i < 4; ++i) {
            const int grow = brow + wm * 64 + i * 16 + (lane >> 4) * 4;
            float* yp = Y + (size_t)grow * NN + gc;
#pragma unroll
            for (int r = 0; r < 4; ++r)
                yp[(size_t)r * NN] = acc[i][j][r] * sj + bj;
        }
    }
}

extern "C" void kernel_launch(void* const* d_in, const int* in_sizes, int n_in,
                              void* d_out, int out_size, void* d_ws, size_t ws_size,
                              hipStream_t stream) {
    const float* x = (const float*)d_in[0];
    const int*   w = (const int*)d_in[1];
    const float* s = (const float*)d_in[2];
    const float* b = (const float*)d_in[3];
    float* y = (float*)d_out;

    const size_t wq_b = (size_t)NN * KK;            // 45.1 MB
    const size_t xq_b = (size_t)MM * KK;            // 8.4 MB
    const size_t need = wq_b + xq_b + 2 * MM * sizeof(float) + 256;
    if (ws_size >= need) {
        char*  Wq    = (char*)d_ws;
        char*  Xq    = Wq + wq_b;
        float* Sx    = (float*)(Xq + xq_b);
        float* SxInv = Sx + MM;
        hipLaunchKernelGGL(rowmax_x,   dim3(MM),   dim3(256), 0, stream, x, Sx, SxInv);
        hipLaunchKernelGGL(quant_pack, dim3(4096), dim3(256), 0, stream, x, w, SxInv, Xq, Wq);
        hipLaunchKernelGGL(gemm_i8, dim3((MM / 256) * (NN / 128)), dim3(512), 0, stream,
                           Xq, Wq, Sx, s, b, y);
    } else {
        hipLaunchKernelGGL(int8lin_fused, dim3((MM / BMF) * (NN / BMF)), dim3(256), 0, stream,
                           x, w, s, b, y);
    }
}